// Round 13
// baseline (1224.980 us; speedup 1.0000x reference)
//
#include <hip/hip_runtime.h>
#include <math.h>

#define NPTS 8192
#define KNN 20
#define CAP 256
#define NT 512               // threads for select kernels
#define MK (NPTS / NT)       // 16 keys per thread (registers)
#define NW (NT / 64)         // 8 waves

static __device__ __forceinline__ unsigned long long umin64(unsigned long long a, unsigned long long b) {
    return a < b ? a : b;
}
static __device__ __forceinline__ unsigned umin32(unsigned a, unsigned b) { return a < b ? a : b; }

// ---------------- row squared norms: bit-faithful replica of np.sum(x*x, -1) ----------------
template<int C>
__global__ void rowsq_np_kernel(const float* __restrict__ X, int ld, float* __restrict__ x2) {
#pragma clang fp contract(off)
    int i = blockIdx.x * blockDim.x + threadIdx.x;
    if (i >= NPTS) return;
    const float* row = X + (long)i * ld;
    float res;
    if (C < 8) {
        res = 0.f;
        for (int c = 0; c < C; ++c) res += row[c] * row[c];
    } else {
        float r[8];
#pragma unroll
        for (int j = 0; j < 8; ++j) r[j] = row[j] * row[j];
        int p = 8;
        for (; p < C - (C % 8); p += 8)
#pragma unroll
            for (int j = 0; j < 8; ++j) r[j] += row[p + j] * row[p + j];
        res = ((r[0] + r[1]) + (r[2] + r[3])) + ((r[4] + r[5]) + (r[6] + r[7]));
        for (; p < C; ++p) res += row[p] * row[p];
    }
    x2[i] = res;
}

// ---------------- X -> SoA (C=3) ----------------
__global__ void soa3_kernel(const float* __restrict__ X, float* __restrict__ X0,
                            float* __restrict__ X1, float* __restrict__ X2) {
    int i = blockIdx.x * blockDim.x + threadIdx.x;
    if (i < NPTS) { X0[i] = X[3 * i]; X1[i] = X[3 * i + 1]; X2[i] = X[3 * i + 2]; }
}

// ---------------- slab transpose: X (row-major, ld) cols[0..C) -> XT[c][j] ----------------
__global__ __launch_bounds__(256) void transpose_kernel(const float* __restrict__ X, int ld, int C,
                                                        float* __restrict__ XT) {
    __shared__ float t[32][33];
    const int jb = blockIdx.x * 32;
    const int cb = blockIdx.y * 32;
    const int tx = threadIdx.x & 31, ty = threadIdx.x >> 5;
#pragma unroll
    for (int k = 0; k < 4; ++k) {
        int j = jb + ty + 8 * k;
        int c = cb + tx;
        t[ty + 8 * k][tx] = (c < C) ? X[(long)j * ld + c] : 0.f;
    }
    __syncthreads();
#pragma unroll
    for (int k = 0; k < 4; ++k) {
        int c = cb + ty + 8 * k;
        int j = jb + tx;
        if (c < C) XT[(long)c * NPTS + j] = t[tx][ty + 8 * k];
    }
}

// ---------------- register-resident count of keys <= B ----------------
__device__ __forceinline__ int count_le_reg(const unsigned* k, unsigned B, int* scal) {
    const int tid = threadIdx.x;
    int cnt = 0;
#pragma unroll
    for (int m = 0; m < MK; ++m) cnt += (k[m] <= B) ? 1 : 0;
#pragma unroll
    for (int o = 32; o >= 1; o >>= 1) cnt += __shfl_down(cnt, (unsigned)o);
    if ((tid & 63) == 0) scal[tid >> 6] = cnt;
    __syncthreads();
    int tot = 0;
#pragma unroll
    for (int w = 0; w < NW; ++w) tot += scal[w];
    __syncthreads();
    return tot;
}

// ---------------- exact top-K via min-scan sample threshold, keys in REGISTERS ----------------
__device__ __forceinline__ void select20_reg(unsigned* k, unsigned* ured,
                                             unsigned long long* cand, int* scal,
                                             long row, int* __restrict__ idx_out) {
    const int tid = threadIdx.x;
    unsigned s = k[0];              // one sample per thread (j = tid)
    unsigned B; int c;
    for (;;) {
        unsigned m = s;
#pragma unroll
        for (int o = 32; o >= 1; o >>= 1) m = umin32(m, __shfl_down(m, (unsigned)o));
        if ((tid & 63) == 0) ured[tid >> 6] = m;
        __syncthreads();
        B = ured[0];
#pragma unroll
        for (int w = 1; w < NW; ++w) B = umin32(B, ured[w]);
        __syncthreads();
        c = count_le_reg(k, B, scal);
        if (c >= KNN) break;
        if (s <= B) s = 0xFFFFFFFFu;   // deactivate exhausted samples
    }
    if (tid == 0) scal[8] = 0;
    __syncthreads();

    if (c <= CAP) {
#pragma unroll
        for (int m = 0; m < MK; ++m) {
            if (k[m] <= B) {
                int j = tid + NT * m;
                int p = atomicAdd(&scal[8], 1);    // p < c <= CAP guaranteed
                cand[p] = (((unsigned long long)k[m]) << 32) | (unsigned)j;
            }
        }
        __syncthreads();
        const int nc = scal[8];
        if (tid < 64) {
            unsigned long long cc[4];
#pragma unroll
            for (int q = 0; q < 4; ++q) { int i = tid + 64 * q; cc[q] = (i < nc) ? cand[i] : ~0ull; }
            for (int it = 0; it < KNN; ++it) {
                unsigned long long g = umin64(umin64(cc[0], cc[1]), umin64(cc[2], cc[3]));
#pragma unroll
                for (int o = 1; o < 64; o <<= 1) g = umin64(g, __shfl_xor(g, o));
                if (tid == 0) idx_out[row * KNN + it] = (int)(unsigned)(g & 0xFFFFFFFFull);
#pragma unroll
                for (int q = 0; q < 4; ++q) if (cc[q] == g) cc[q] = ~0ull;
            }
        }
    } else {
        // exact fallback (massive ties) — not expected; cand[0..NW) reused as partials
        for (int it = 0; it < KNN; ++it) {
            unsigned long long best = ~0ull;
#pragma unroll
            for (int m = 0; m < MK; ++m)
                best = umin64(best, (((unsigned long long)k[m]) << 32) | (unsigned)(tid + NT * m));
#pragma unroll
            for (int o = 1; o < 64; o <<= 1) best = umin64(best, __shfl_xor(best, o));
            if ((tid & 63) == 0) cand[tid >> 6] = best;
            __syncthreads();
            unsigned long long g = cand[0];
#pragma unroll
            for (int w = 1; w < NW; ++w) g = umin64(g, cand[w]);
            int j = (int)(unsigned)(g & 0xFFFFFFFFull);
            if (tid == 0) idx_out[row * KNN + it] = j;
            __syncthreads();
            int mi = j / NT;
#pragma unroll
            for (int m = 0; m < MK; ++m)
                if (m == mi && tid == (j & (NT - 1))) k[m] = 0xFFFFFFFFu;
            __syncthreads();
        }
    }
}

// ---------------- stage-1 fused: C=3 distances (SoA) + top-K, keys in registers ----------------
__global__ __launch_bounds__(NT) void knn3_fused_kernel(const float* __restrict__ X0,
                                                        const float* __restrict__ X1,
                                                        const float* __restrict__ X2,
                                                        const float* __restrict__ x2,
                                                        int* __restrict__ idx_out) {
    __shared__ unsigned ured[NW];
    __shared__ unsigned long long cand[CAP];
    __shared__ int scal[16];
    unsigned k[MK];
    const int tid = threadIdx.x;
    const int row = blockIdx.x;
    const float xi0 = X0[row], xi1 = X1[row], xi2 = X2[row];
    const float x2i = x2[row];

#pragma unroll
    for (int m = 0; m < MK; ++m) {
        int j = tid + NT * m;
        float accv = 0.f;                       // identical ascending-c fmaf chain
        accv = fmaf(xi0, X0[j], accv);
        accv = fmaf(xi1, X1[j], accv);
        accv = fmaf(xi2, X2[j], accv);
        float d = (x2i + x2[j]) - 2.f * accv;
        unsigned u = __float_as_uint(d);
        k[m] = (u & 0x80000000u) ? ~u : (u | 0x80000000u);
    }
    select20_reg(k, ured, cand, scal, row, idx_out);
}

// ---------------- top-K from materialized dist rows, keys in registers ----------------
__global__ __launch_bounds__(NT) void topk_kernel(const float* __restrict__ dist, int* __restrict__ idx_out,
                                                  int rowbase) {
    __shared__ unsigned ured[NW];
    __shared__ unsigned long long cand[CAP];
    __shared__ int scal[16];
    unsigned k[MK];
    const int tid = threadIdx.x;
    const long row = rowbase + blockIdx.x;
    const float* drow = dist + (long)blockIdx.x * NPTS;

#pragma unroll
    for (int m = 0; m < MK; ++m) {
        unsigned u = __float_as_uint(drow[tid + NT * m]);
        k[m] = (u & 0x80000000u) ? ~u : (u | 0x80000000u);
    }
    select20_reg(k, ured, cand, scal, row, idx_out);
}

// ---------------- pairwise distance (fp32), 128x128, dbuf LDS (1 barrier/tile) ----------------
// Staging from K-major slab XT[c][j]: float4 global loads + b128 LDS writes.
// Bit-exact: per-element ascending-k fmaf chains; pads fmaf(0,0,acc).
__global__ __launch_bounds__(256) void dist128_kernel(const float* __restrict__ XT, int C,
                                                      const float* __restrict__ x2,
                                                      float* __restrict__ dist, int i0base) {
    __shared__ float As[2][16][132];
    __shared__ float Bs[2][16][132];
    const int tid = threadIdx.x;
    const int i0 = i0base + blockIdx.y * 128;
    const int j0 = blockIdx.x * 128;
    const int ty = tid >> 4, tx = tid & 15;
    const int lc = tid >> 5;            // loader col 0..7 (and +8)
    const int lr4 = (tid & 31) * 4;     // loader row group

    const float4 z4 = {0.f, 0.f, 0.f, 0.f};
    float4 ra0, ra1, rb0, rb1;
    float acc[8][8];
#pragma unroll
    for (int a = 0; a < 8; ++a)
#pragma unroll
        for (int b = 0; b < 8; ++b) acc[a][b] = 0.f;

    {
        const bool v0 = (lc < C), v1 = (lc + 8 < C);
        ra0 = v0 ? *(const float4*)&XT[(long)lc * NPTS + i0 + lr4] : z4;
        ra1 = v1 ? *(const float4*)&XT[(long)(lc + 8) * NPTS + i0 + lr4] : z4;
        rb0 = v0 ? *(const float4*)&XT[(long)lc * NPTS + j0 + lr4] : z4;
        rb1 = v1 ? *(const float4*)&XT[(long)(lc + 8) * NPTS + j0 + lr4] : z4;
    }
    *(float4*)&As[0][lc][lr4]     = ra0;
    *(float4*)&As[0][lc + 8][lr4] = ra1;
    *(float4*)&Bs[0][lc][lr4]     = rb0;
    *(float4*)&Bs[0][lc + 8][lr4] = rb1;
    __syncthreads();

    int p = 0;
    for (int k0 = 0; k0 < C; k0 += 16) {
        const bool nxt = (k0 + 16 < C);
        if (nxt) {
            const int c0 = k0 + 16 + lc, c1 = c0 + 8;
            const bool v0 = (c0 < C), v1 = (c1 < C);
            ra0 = v0 ? *(const float4*)&XT[(long)c0 * NPTS + i0 + lr4] : z4;
            ra1 = v1 ? *(const float4*)&XT[(long)c1 * NPTS + i0 + lr4] : z4;
            rb0 = v0 ? *(const float4*)&XT[(long)c0 * NPTS + j0 + lr4] : z4;
            rb1 = v1 ? *(const float4*)&XT[(long)c1 * NPTS + j0 + lr4] : z4;
        }
#pragma unroll
        for (int kk = 0; kk < 16; ++kk) {
            float4 a0 = *(const float4*)&As[p][kk][ty * 4];
            float4 a1 = *(const float4*)&As[p][kk][ty * 4 + 64];
            float4 b0 = *(const float4*)&Bs[p][kk][tx * 4];
            float4 b1 = *(const float4*)&Bs[p][kk][tx * 4 + 64];
            float av[8] = {a0.x, a0.y, a0.z, a0.w, a1.x, a1.y, a1.z, a1.w};
            float bv[8] = {b0.x, b0.y, b0.z, b0.w, b1.x, b1.y, b1.z, b1.w};
#pragma unroll
            for (int ii = 0; ii < 8; ++ii)
#pragma unroll
                for (int jj = 0; jj < 8; ++jj)
                    acc[ii][jj] = fmaf(av[ii], bv[jj], acc[ii][jj]);
        }
        if (nxt) {
            *(float4*)&As[p ^ 1][lc][lr4]     = ra0;
            *(float4*)&As[p ^ 1][lc + 8][lr4] = ra1;
            *(float4*)&Bs[p ^ 1][lc][lr4]     = rb0;
            *(float4*)&Bs[p ^ 1][lc + 8][lr4] = rb1;
        }
        __syncthreads();
        p ^= 1;
    }

    float xj[8];
#pragma unroll
    for (int u = 0; u < 2; ++u)
#pragma unroll
        for (int cc = 0; cc < 4; ++cc) xj[u * 4 + cc] = x2[j0 + tx * 4 + 64 * u + cc];
#pragma unroll
    for (int v = 0; v < 2; ++v) {
#pragma unroll
        for (int rr = 0; rr < 4; ++rr) {
            int rloc = blockIdx.y * 128 + ty * 4 + 64 * v + rr;
            float xi = x2[i0base + rloc];
            int ii = v * 4 + rr;
#pragma unroll
            for (int u = 0; u < 2; ++u) {
                float4 o;
                o.x = (xi + xj[u * 4 + 0]) - 2.f * acc[ii][u * 4 + 0];
                o.y = (xi + xj[u * 4 + 1]) - 2.f * acc[ii][u * 4 + 1];
                o.z = (xi + xj[u * 4 + 2]) - 2.f * acc[ii][u * 4 + 2];
                o.w = (xi + xj[u * 4 + 3]) - 2.f * acc[ii][u * 4 + 3];
                *(float4*)&dist[(long)rloc * NPTS + j0 + tx * 4 + 64 * u] = o;
            }
        }
    }
}

// ---------------- erosion edge-conv (fp32, order-free exact) ----------------
template<int F, int C>
__global__ void erode_kernel(const float* __restrict__ X, int ld, const int* __restrict__ idx,
                             const float* __restrict__ w, float* __restrict__ out, int ldo) {
    __shared__ int nidx[KNN];
    __shared__ float neigh[KNN * C];
    const int tid = threadIdx.x;
    const int row = blockIdx.x;
    if (tid < KNN) nidx[tid] = idx[row * KNN + tid];
    __syncthreads();
    for (int t = tid; t < KNN * C; t += blockDim.x) {
        int k = t / C, c = t % C;
        neigh[t] = X[(long)nidx[k] * ld + c];
    }
    __syncthreads();
    if (tid < F * C) {
        int f = tid / C, c = tid % C;
        float m = neigh[c] - w[f * KNN * C + c];
        for (int k = 1; k < KNN; ++k)
            m = fminf(m, neigh[k * C + c] - w[(f * KNN + k) * C + c]);
        out[(long)row * ldo + tid] = m;
    }
}

// ---------------- fp32 GEMM 128x128 from K-major A (lin1), dbuf, float4 staging ----------------
// A from AT[k][i] (ld NPTS); B row-major [K][N], N%128==0, M%128==0; guards on k only.
template<int RELU>
__global__ __launch_bounds__(256) void gemm128T_kernel(const float* __restrict__ AT,
                                                       const float* __restrict__ B,
                                                       const float* __restrict__ bias, float* __restrict__ Cm,
                                                       int K, int N, int i0base) {
    __shared__ float As[2][16][132];
    __shared__ float Bs[2][16][132];
    const int tid = threadIdx.x;
    const int i0 = i0base + blockIdx.y * 128;
    const int j0 = blockIdx.x * 128;
    const int ty = tid >> 4, tx = tid & 15;
    const int lc = tid >> 5;
    const int lr4 = (tid & 31) * 4;

    const float4 z4 = {0.f, 0.f, 0.f, 0.f};
    float4 ra0, ra1, rb0, rb1;
    float acc[8][8];
#pragma unroll
    for (int a = 0; a < 8; ++a)
#pragma unroll
        for (int b = 0; b < 8; ++b) acc[a][b] = 0.f;

    {
        const bool v0 = (lc < K), v1 = (lc + 8 < K);
        ra0 = v0 ? *(const float4*)&AT[(long)lc * NPTS + i0 + lr4] : z4;
        ra1 = v1 ? *(const float4*)&AT[(long)(lc + 8) * NPTS + i0 + lr4] : z4;
        rb0 = v0 ? *(const float4*)&B[(long)lc * N + j0 + lr4] : z4;
        rb1 = v1 ? *(const float4*)&B[(long)(lc + 8) * N + j0 + lr4] : z4;
    }
    *(float4*)&As[0][lc][lr4]     = ra0;
    *(float4*)&As[0][lc + 8][lr4] = ra1;
    *(float4*)&Bs[0][lc][lr4]     = rb0;
    *(float4*)&Bs[0][lc + 8][lr4] = rb1;
    __syncthreads();

    int p = 0;
    for (int k0 = 0; k0 < K; k0 += 16) {
        const bool nxt = (k0 + 16 < K);
        if (nxt) {
            const int c0 = k0 + 16 + lc, c1 = c0 + 8;
            const bool v0 = (c0 < K), v1 = (c1 < K);
            ra0 = v0 ? *(const float4*)&AT[(long)c0 * NPTS + i0 + lr4] : z4;
            ra1 = v1 ? *(const float4*)&AT[(long)c1 * NPTS + i0 + lr4] : z4;
            rb0 = v0 ? *(const float4*)&B[(long)c0 * N + j0 + lr4] : z4;
            rb1 = v1 ? *(const float4*)&B[(long)c1 * N + j0 + lr4] : z4;
        }
#pragma unroll
        for (int kk = 0; kk < 16; ++kk) {
            float4 a0 = *(const float4*)&As[p][kk][ty * 4];
            float4 a1 = *(const float4*)&As[p][kk][ty * 4 + 64];
            float4 b0 = *(const float4*)&Bs[p][kk][tx * 4];
            float4 b1 = *(const float4*)&Bs[p][kk][tx * 4 + 64];
            float av[8] = {a0.x, a0.y, a0.z, a0.w, a1.x, a1.y, a1.z, a1.w};
            float bv[8] = {b0.x, b0.y, b0.z, b0.w, b1.x, b1.y, b1.z, b1.w};
#pragma unroll
            for (int ii = 0; ii < 8; ++ii)
#pragma unroll
                for (int jj = 0; jj < 8; ++jj)
                    acc[ii][jj] = fmaf(av[ii], bv[jj], acc[ii][jj]);
        }
        if (nxt) {
            *(float4*)&As[p ^ 1][lc][lr4]     = ra0;
            *(float4*)&As[p ^ 1][lc + 8][lr4] = ra1;
            *(float4*)&Bs[p ^ 1][lc][lr4]     = rb0;
            *(float4*)&Bs[p ^ 1][lc + 8][lr4] = rb1;
        }
        __syncthreads();
        p ^= 1;
    }

#pragma unroll
    for (int v = 0; v < 2; ++v) {
#pragma unroll
        for (int rr = 0; rr < 4; ++rr) {
            int i = i0 + ty * 4 + 64 * v + rr;
            int ii = v * 4 + rr;
#pragma unroll
            for (int u = 0; u < 2; ++u) {
                int j = j0 + tx * 4 + 64 * u;
                float4 o;
                o.x = acc[ii][u * 4 + 0] + bias[j + 0];
                o.y = acc[ii][u * 4 + 1] + bias[j + 1];
                o.z = acc[ii][u * 4 + 2] + bias[j + 2];
                o.w = acc[ii][u * 4 + 3] + bias[j + 3];
                if (RELU) {
                    o.x = fmaxf(o.x, 0.f); o.y = fmaxf(o.y, 0.f);
                    o.z = fmaxf(o.z, 0.f); o.w = fmaxf(o.w, 0.f);
                }
                *(float4*)&Cm[(long)(i - i0base) * N + j] = o;
            }
        }
    }
}

// ---------------- fp32 GEMM 64x64 (layers 2-4), BK=32 prefetch ----------------
template<int RELU>
__global__ __launch_bounds__(256) void gemm_kernel(const float* __restrict__ A, const float* __restrict__ B,
                                                   const float* __restrict__ bias, float* __restrict__ Cm,
                                                   int K, int N) {
    __shared__ float As[32][68];
    __shared__ float Bs[32][68];
    const int tid = threadIdx.x;
    const int i0 = blockIdx.y * 64, j0 = blockIdx.x * 64;
    const int ty = tid >> 4, tx = tid & 15;
    const int la_c = tid & 31, la_r = tid >> 5;
    const int lb_n = tid & 63, lb_k = tid >> 6;

    float ra[8], rb[8];
    float acc[4][4];
#pragma unroll
    for (int a = 0; a < 4; ++a)
#pragma unroll
        for (int b = 0; b < 4; ++b) acc[a][b] = 0.f;

    {
        const bool bn = (j0 + lb_n < N);
#pragma unroll
        for (int q = 0; q < 8; ++q) {
            int r = la_r + 8 * q;
            ra[q] = (la_c < K) ? A[(long)(i0 + r) * K + la_c] : 0.f;
            int kk = lb_k + 4 * q;
            rb[q] = (kk < K && bn) ? B[(long)kk * N + j0 + lb_n] : 0.f;
        }
    }

    for (int k0 = 0; k0 < K; k0 += 32) {
#pragma unroll
        for (int q = 0; q < 8; ++q) {
            As[la_c][la_r + 8 * q] = ra[q];
            Bs[lb_k + 4 * q][lb_n] = rb[q];
        }
        __syncthreads();
        if (k0 + 32 < K) {
            const bool bn = (j0 + lb_n < N);
#pragma unroll
            for (int q = 0; q < 8; ++q) {
                int r = la_r + 8 * q;
                ra[q] = (k0 + 32 + la_c < K) ? A[(long)(i0 + r) * K + k0 + 32 + la_c] : 0.f;
                int kk = k0 + 32 + lb_k + 4 * q;
                rb[q] = (kk < K && bn) ? B[(long)kk * N + j0 + lb_n] : 0.f;
            }
        }
#pragma unroll
        for (int kk = 0; kk < 32; ++kk) {
            float4 a4 = *(const float4*)&As[kk][ty * 4];
            float4 b4 = *(const float4*)&Bs[kk][tx * 4];
            float av[4] = {a4.x, a4.y, a4.z, a4.w};
            float bv[4] = {b4.x, b4.y, b4.z, b4.w};
#pragma unroll
            for (int ii = 0; ii < 4; ++ii)
#pragma unroll
                for (int jj = 0; jj < 4; ++jj)
                    acc[ii][jj] = fmaf(av[ii], bv[jj], acc[ii][jj]);
        }
        __syncthreads();
    }

#pragma unroll
    for (int ii = 0; ii < 4; ++ii) {
        int i = i0 + ty * 4 + ii;
#pragma unroll
        for (int jj = 0; jj < 4; ++jj) {
            int j = j0 + tx * 4 + jj;
            if (j < N) {
                float v = acc[ii][jj] + bias[j];
                if (RELU) v = fmaxf(v, 0.f);
                Cm[(long)i * N + j] = v;
            }
        }
    }
}

// ---------------- log_softmax over 40 cols, wave per row, in place ----------------
__global__ void logsoftmax_kernel(float* __restrict__ out) {
    const int lane = threadIdx.x & 63;
    const int wid = threadIdx.x >> 6;
    const int row = blockIdx.x * 4 + wid;
    float* o = out + (long)row * 40;
    float v = (lane < 40) ? o[lane] : -INFINITY;
    float m = v;
#pragma unroll
    for (int off = 1; off < 64; off <<= 1) m = fmaxf(m, __shfl_xor(m, off));
    float e = (lane < 40) ? expf(v - m) : 0.f;
    float s = e;
#pragma unroll
    for (int off = 1; off < 64; off <<= 1) s += __shfl_xor(s, off);
    float r = (v - m) - logf(s);
    if (lane < 40) o[lane] = r;
}

extern "C" void kernel_launch(void* const* d_in, const int* in_sizes, int n_in,
                              void* d_out, int out_size, void* d_ws, size_t ws_size,
                              hipStream_t stream) {
    (void)in_sizes; (void)n_in; (void)out_size;
    const float* x     = (const float*)d_in[0];
    const float* w1    = (const float*)d_in[1];
    const float* w2    = (const float*)d_in[2];
    const float* w3    = (const float*)d_in[3];
    const float* lin1w = (const float*)d_in[4];
    const float* lin1b = (const float*)d_in[5];
    const float* wa    = (const float*)d_in[6];
    const float* ba    = (const float*)d_in[7];
    const float* wb    = (const float*)d_in[8];
    const float* bb    = (const float*)d_in[9];
    const float* wo    = (const float*)d_in[10];
    const float* bo    = (const float*)d_in[11];
    float* outp = (float*)d_out;

    // ---- ws_size-adaptive layout ----
    char* ws = (char*)d_ws;
    size_t off = 0;
    auto take = [&](size_t bytes) { char* p = ws + off; off += (bytes + 255) & ~(size_t)255; return p; };
    float* x2  = (float*)take((size_t)NPTS * 4);
    int*   idx = (int*)  take((size_t)NPTS * KNN * 4);
    float* h0  = (float*)take((size_t)NPTS * 420 * 4);
    float* sx0 = (float*)take((size_t)NPTS * 4);
    float* sx1 = (float*)take((size_t)NPTS * 4);
    float* sx2 = (float*)take((size_t)NPTS * 4);
    float* XT  = (float*)take((size_t)NPTS * 420 * 4);   // K-major h0 (progressively filled)
    size_t rest = (ws_size > off) ? (ws_size - off) : 0;
    char*  scratch = ws + off;

    int cr = (int)(rest / ((size_t)NPTS * 4));   // fp32 dist chunk rows
    if (cr > 4096) cr = 4096;                    // 128 MB chunk: topk re-read stays L3-resident
    cr &= ~127;
    if (cr < 128) cr = 128;
    float* dist = (float*)scratch;

    int mr = (int)(rest / 5632);                 // fp32 MLP chunk rows
    if (mr > NPTS) mr = NPTS;
    mr &= ~127;
    if (mr < 128) mr = 128;

    dim3 b256(256);
    dim3 b512(NT);
    dim3 grow(NPTS);

    // ---- stage 1: fused knn(x, C=3) -> erode -> x1 = h0[:, 0:60]
    rowsq_np_kernel<3><<<dim3(32), b256, 0, stream>>>(x, 3, x2);
    soa3_kernel<<<dim3(32), b256, 0, stream>>>(x, sx0, sx1, sx2);
    knn3_fused_kernel<<<grow, b512, 0, stream>>>(sx0, sx1, sx2, x2, idx);
    erode_kernel<20, 3><<<grow, dim3(64), 0, stream>>>(x, 3, idx, w1, h0 + 0, 420);

    // ---- stage 2: knn(x1, C=60) -> erode -> x2f = h0[:, 60:180]
    rowsq_np_kernel<60><<<dim3(32), b256, 0, stream>>>(h0, 420, x2);
    transpose_kernel<<<dim3(NPTS / 32, 2), b256, 0, stream>>>(h0, 420, 60, XT);
    for (int r0 = 0; r0 < NPTS; r0 += cr) {
        int rows = (NPTS - r0 < cr) ? (NPTS - r0) : cr;
        dist128_kernel<<<dim3(64, rows / 128), b256, 0, stream>>>(XT, 60, x2, dist, r0);
        topk_kernel<<<dim3(rows), b512, 0, stream>>>(dist, idx, r0);
    }
    erode_kernel<2, 60><<<grow, dim3(128), 0, stream>>>(h0, 420, idx, w2, h0 + 60, 420);

    // ---- stage 3: knn(x2f, C=120) -> erode -> x3 = h0[:, 180:420]
    rowsq_np_kernel<120><<<dim3(32), b256, 0, stream>>>(h0 + 60, 420, x2);
    transpose_kernel<<<dim3(NPTS / 32, 4), b256, 0, stream>>>(h0 + 60, 420, 120, XT + (size_t)60 * NPTS);
    for (int r0 = 0; r0 < NPTS; r0 += cr) {
        int rows = (NPTS - r0 < cr) ? (NPTS - r0) : cr;
        dist128_kernel<<<dim3(64, rows / 128), b256, 0, stream>>>(XT + (size_t)60 * NPTS, 120, x2, dist, r0);
        topk_kernel<<<dim3(rows), b512, 0, stream>>>(dist, idx, r0);
    }
    erode_kernel<2, 120><<<grow, dim3(256), 0, stream>>>(h0 + 60, 420, idx, w3, h0 + 180, 420);

    // ---- finish K-major h0: cols 180..420
    transpose_kernel<<<dim3(NPTS / 32, 8), b256, 0, stream>>>(h0 + 180, 420, 240, XT + (size_t)180 * NPTS);

    // ---- MLP (row-chunked; h1|h2|h3 live in scratch)
    for (int r0 = 0; r0 < NPTS; r0 += mr) {
        int rows = (NPTS - r0 < mr) ? (NPTS - r0) : mr;
        float* h1c = (float*)scratch;
        float* h2c = h1c + (size_t)mr * 1024;
        float* h3c = h2c + (size_t)mr * 256;
        gemm128T_kernel<1><<<dim3(8, rows / 128), b256, 0, stream>>>(XT, lin1w, lin1b, h1c, 420, 1024, r0);
        gemm_kernel<1><<<dim3(4, rows / 64), b256, 0, stream>>>(h1c, wa, ba, h2c, 1024, 256);
        gemm_kernel<1><<<dim3(2, rows / 64), b256, 0, stream>>>(h2c, wb, bb, h3c, 256, 128);
        gemm_kernel<0><<<dim3(1, rows / 64), b256, 0, stream>>>(h3c, wo, bo, outp + (long)r0 * 40, 128, 40);
        logsoftmax_kernel<<<dim3(rows / 4), b256, 0, stream>>>(outp + (long)r0 * 40);
    }
}

// Round 14
// 973.769 us; speedup vs baseline: 1.2580x; 1.2580x over previous
//
#include <hip/hip_runtime.h>
#include <math.h>

#define NPTS 8192
#define KNN 20
#define CAP 256
#define NT 512               // threads for select kernels
#define MK (NPTS / NT)       // 16 keys per thread (registers)
#define NW (NT / 64)         // 8 waves

static __device__ __forceinline__ unsigned long long umin64(unsigned long long a, unsigned long long b) {
    return a < b ? a : b;
}
static __device__ __forceinline__ unsigned umin32(unsigned a, unsigned b) { return a < b ? a : b; }

// ---------------- row squared norms: bit-faithful replica of np.sum(x*x, -1) ----------------
template<int C>
__global__ void rowsq_np_kernel(const float* __restrict__ X, int ld, float* __restrict__ x2) {
#pragma clang fp contract(off)
    int i = blockIdx.x * blockDim.x + threadIdx.x;
    if (i >= NPTS) return;
    const float* row = X + (long)i * ld;
    float res;
    if (C < 8) {
        res = 0.f;
        for (int c = 0; c < C; ++c) res += row[c] * row[c];
    } else {
        float r[8];
#pragma unroll
        for (int j = 0; j < 8; ++j) r[j] = row[j] * row[j];
        int p = 8;
        for (; p < C - (C % 8); p += 8)
#pragma unroll
            for (int j = 0; j < 8; ++j) r[j] += row[p + j] * row[p + j];
        res = ((r[0] + r[1]) + (r[2] + r[3])) + ((r[4] + r[5]) + (r[6] + r[7]));
        for (; p < C; ++p) res += row[p] * row[p];
    }
    x2[i] = res;
}

// ---------------- X -> SoA (C=3) ----------------
__global__ void soa3_kernel(const float* __restrict__ X, float* __restrict__ X0,
                            float* __restrict__ X1, float* __restrict__ X2) {
    int i = blockIdx.x * blockDim.x + threadIdx.x;
    if (i < NPTS) { X0[i] = X[3 * i]; X1[i] = X[3 * i + 1]; X2[i] = X[3 * i + 2]; }
}

// ---------------- slab transpose: X (row-major, ld) cols[0..C) -> XT[c][j] ----------------
__global__ __launch_bounds__(256) void transpose_kernel(const float* __restrict__ X, int ld, int C,
                                                        float* __restrict__ XT) {
    __shared__ float t[32][33];
    const int jb = blockIdx.x * 32;
    const int cb = blockIdx.y * 32;
    const int tx = threadIdx.x & 31, ty = threadIdx.x >> 5;
#pragma unroll
    for (int k = 0; k < 4; ++k) {
        int j = jb + ty + 8 * k;
        int c = cb + tx;
        t[ty + 8 * k][tx] = (c < C) ? X[(long)j * ld + c] : 0.f;
    }
    __syncthreads();
#pragma unroll
    for (int k = 0; k < 4; ++k) {
        int c = cb + ty + 8 * k;
        int j = jb + tx;
        if (c < C) XT[(long)c * NPTS + j] = t[tx][ty + 8 * k];
    }
}

// ---------------- register-resident count of keys <= B ----------------
__device__ __forceinline__ int count_le_reg(const unsigned* k, unsigned B, int* scal) {
    const int tid = threadIdx.x;
    int cnt = 0;
#pragma unroll
    for (int m = 0; m < MK; ++m) cnt += (k[m] <= B) ? 1 : 0;
#pragma unroll
    for (int o = 32; o >= 1; o >>= 1) cnt += __shfl_down(cnt, (unsigned)o);
    if ((tid & 63) == 0) scal[tid >> 6] = cnt;
    __syncthreads();
    int tot = 0;
#pragma unroll
    for (int w = 0; w < NW; ++w) tot += scal[w];
    __syncthreads();
    return tot;
}

// ---------------- exact top-K via min-scan sample threshold, keys in REGISTERS ----------------
__device__ __forceinline__ void select20_reg(unsigned* k, unsigned* ured,
                                             unsigned long long* cand, int* scal,
                                             long row, int* __restrict__ idx_out) {
    const int tid = threadIdx.x;
    unsigned s = k[0];              // one sample per thread (j = tid)
    unsigned B; int c;
    for (;;) {
        unsigned m = s;
#pragma unroll
        for (int o = 32; o >= 1; o >>= 1) m = umin32(m, __shfl_down(m, (unsigned)o));
        if ((tid & 63) == 0) ured[tid >> 6] = m;
        __syncthreads();
        B = ured[0];
#pragma unroll
        for (int w = 1; w < NW; ++w) B = umin32(B, ured[w]);
        __syncthreads();
        c = count_le_reg(k, B, scal);
        if (c >= KNN) break;
        if (s <= B) s = 0xFFFFFFFFu;   // deactivate exhausted samples
    }
    if (tid == 0) scal[8] = 0;
    __syncthreads();

    if (c <= CAP) {
#pragma unroll
        for (int m = 0; m < MK; ++m) {
            if (k[m] <= B) {
                int j = tid + NT * m;
                int p = atomicAdd(&scal[8], 1);    // p < c <= CAP guaranteed
                cand[p] = (((unsigned long long)k[m]) << 32) | (unsigned)j;
            }
        }
        __syncthreads();
        const int nc = scal[8];
        if (tid < 64) {
            unsigned long long cc[4];
#pragma unroll
            for (int q = 0; q < 4; ++q) { int i = tid + 64 * q; cc[q] = (i < nc) ? cand[i] : ~0ull; }
            for (int it = 0; it < KNN; ++it) {
                unsigned long long g = umin64(umin64(cc[0], cc[1]), umin64(cc[2], cc[3]));
#pragma unroll
                for (int o = 1; o < 64; o <<= 1) g = umin64(g, __shfl_xor(g, o));
                if (tid == 0) idx_out[row * KNN + it] = (int)(unsigned)(g & 0xFFFFFFFFull);
#pragma unroll
                for (int q = 0; q < 4; ++q) if (cc[q] == g) cc[q] = ~0ull;
            }
        }
    } else {
        // exact fallback (massive ties) — not expected; cand[0..NW) reused as partials
        for (int it = 0; it < KNN; ++it) {
            unsigned long long best = ~0ull;
#pragma unroll
            for (int m = 0; m < MK; ++m)
                best = umin64(best, (((unsigned long long)k[m]) << 32) | (unsigned)(tid + NT * m));
#pragma unroll
            for (int o = 1; o < 64; o <<= 1) best = umin64(best, __shfl_xor(best, o));
            if ((tid & 63) == 0) cand[tid >> 6] = best;
            __syncthreads();
            unsigned long long g = cand[0];
#pragma unroll
            for (int w = 1; w < NW; ++w) g = umin64(g, cand[w]);
            int j = (int)(unsigned)(g & 0xFFFFFFFFull);
            if (tid == 0) idx_out[row * KNN + it] = j;
            __syncthreads();
            int mi = j / NT;
#pragma unroll
            for (int m = 0; m < MK; ++m)
                if (m == mi && tid == (j & (NT - 1))) k[m] = 0xFFFFFFFFu;
            __syncthreads();
        }
    }
}

// ---------------- stage-1 fused: C=3 distances (SoA) + top-K, keys in registers ----------------
__global__ __launch_bounds__(NT) void knn3_fused_kernel(const float* __restrict__ X0,
                                                        const float* __restrict__ X1,
                                                        const float* __restrict__ X2,
                                                        const float* __restrict__ x2,
                                                        int* __restrict__ idx_out) {
    __shared__ unsigned ured[NW];
    __shared__ unsigned long long cand[CAP];
    __shared__ int scal[16];
    unsigned k[MK];
    const int tid = threadIdx.x;
    const int row = blockIdx.x;
    const float xi0 = X0[row], xi1 = X1[row], xi2 = X2[row];
    const float x2i = x2[row];

#pragma unroll
    for (int m = 0; m < MK; ++m) {
        int j = tid + NT * m;
        float accv = 0.f;                       // identical ascending-c fmaf chain
        accv = fmaf(xi0, X0[j], accv);
        accv = fmaf(xi1, X1[j], accv);
        accv = fmaf(xi2, X2[j], accv);
        float d = (x2i + x2[j]) - 2.f * accv;
        unsigned u = __float_as_uint(d);
        k[m] = (u & 0x80000000u) ? ~u : (u | 0x80000000u);
    }
    select20_reg(k, ured, cand, scal, row, idx_out);
}

// ---------------- top-K from materialized dist rows, keys in registers ----------------
__global__ __launch_bounds__(NT) void topk_kernel(const float* __restrict__ dist, int* __restrict__ idx_out,
                                                  int rowbase) {
    __shared__ unsigned ured[NW];
    __shared__ unsigned long long cand[CAP];
    __shared__ int scal[16];
    unsigned k[MK];
    const int tid = threadIdx.x;
    const long row = rowbase + blockIdx.x;
    const float* drow = dist + (long)blockIdx.x * NPTS;

#pragma unroll
    for (int m = 0; m < MK; ++m) {
        unsigned u = __float_as_uint(drow[tid + NT * m]);
        k[m] = (u & 0x80000000u) ? ~u : (u | 0x80000000u);
    }
    select20_reg(k, ured, cand, scal, row, idx_out);
}

// ---------------- pairwise distance (fp32), 128x128 tile, 8x8 microtile, BK=16 prefetch ----------------
// SINGLE-buffer LDS (round-12 proven: 96 VGPR, ~5 blocks/CU). Staging from K-major XT[c][j]:
// float4 coalesced global loads + b128 LDS writes. 16B-stride LDS reads (2-way = free).
// Bit-exact: per-element ascending-k fmaf chains; pads fmaf(0,0,acc).
__global__ __launch_bounds__(256) void dist128_kernel(const float* __restrict__ XT, int C,
                                                      const float* __restrict__ x2,
                                                      float* __restrict__ dist, int i0base) {
    __shared__ float As[16][132];
    __shared__ float Bs[16][132];
    const int tid = threadIdx.x;
    const int i0 = i0base + blockIdx.y * 128;
    const int j0 = blockIdx.x * 128;
    const int ty = tid >> 4, tx = tid & 15;
    const int lc = tid >> 5;            // loader col 0..7 (and +8)
    const int lr4 = (tid & 31) * 4;     // loader row group

    const float4 z4 = {0.f, 0.f, 0.f, 0.f};
    float4 ra0, ra1, rb0, rb1;
    float acc[8][8];
#pragma unroll
    for (int a = 0; a < 8; ++a)
#pragma unroll
        for (int b = 0; b < 8; ++b) acc[a][b] = 0.f;

    {
        const bool v0 = (lc < C), v1 = (lc + 8 < C);
        ra0 = v0 ? *(const float4*)&XT[(long)lc * NPTS + i0 + lr4] : z4;
        ra1 = v1 ? *(const float4*)&XT[(long)(lc + 8) * NPTS + i0 + lr4] : z4;
        rb0 = v0 ? *(const float4*)&XT[(long)lc * NPTS + j0 + lr4] : z4;
        rb1 = v1 ? *(const float4*)&XT[(long)(lc + 8) * NPTS + j0 + lr4] : z4;
    }

    for (int k0 = 0; k0 < C; k0 += 16) {
        *(float4*)&As[lc][lr4]     = ra0;
        *(float4*)&As[lc + 8][lr4] = ra1;
        *(float4*)&Bs[lc][lr4]     = rb0;
        *(float4*)&Bs[lc + 8][lr4] = rb1;
        __syncthreads();
        if (k0 + 16 < C) {
            const int c0 = k0 + 16 + lc, c1 = c0 + 8;
            const bool v0 = (c0 < C), v1 = (c1 < C);
            ra0 = v0 ? *(const float4*)&XT[(long)c0 * NPTS + i0 + lr4] : z4;
            ra1 = v1 ? *(const float4*)&XT[(long)c1 * NPTS + i0 + lr4] : z4;
            rb0 = v0 ? *(const float4*)&XT[(long)c0 * NPTS + j0 + lr4] : z4;
            rb1 = v1 ? *(const float4*)&XT[(long)c1 * NPTS + j0 + lr4] : z4;
        }
#pragma unroll
        for (int kk = 0; kk < 16; ++kk) {
            float4 a0 = *(const float4*)&As[kk][ty * 4];
            float4 a1 = *(const float4*)&As[kk][ty * 4 + 64];
            float4 b0 = *(const float4*)&Bs[kk][tx * 4];
            float4 b1 = *(const float4*)&Bs[kk][tx * 4 + 64];
            float av[8] = {a0.x, a0.y, a0.z, a0.w, a1.x, a1.y, a1.z, a1.w};
            float bv[8] = {b0.x, b0.y, b0.z, b0.w, b1.x, b1.y, b1.z, b1.w};
#pragma unroll
            for (int ii = 0; ii < 8; ++ii)
#pragma unroll
                for (int jj = 0; jj < 8; ++jj)
                    acc[ii][jj] = fmaf(av[ii], bv[jj], acc[ii][jj]);
        }
        __syncthreads();
    }

    float xj[8];
#pragma unroll
    for (int u = 0; u < 2; ++u)
#pragma unroll
        for (int cc = 0; cc < 4; ++cc) xj[u * 4 + cc] = x2[j0 + tx * 4 + 64 * u + cc];
#pragma unroll
    for (int v = 0; v < 2; ++v) {
#pragma unroll
        for (int rr = 0; rr < 4; ++rr) {
            int rloc = blockIdx.y * 128 + ty * 4 + 64 * v + rr;
            float xi = x2[i0base + rloc];
            int ii = v * 4 + rr;
#pragma unroll
            for (int u = 0; u < 2; ++u) {
                float4 o;
                o.x = (xi + xj[u * 4 + 0]) - 2.f * acc[ii][u * 4 + 0];
                o.y = (xi + xj[u * 4 + 1]) - 2.f * acc[ii][u * 4 + 1];
                o.z = (xi + xj[u * 4 + 2]) - 2.f * acc[ii][u * 4 + 2];
                o.w = (xi + xj[u * 4 + 3]) - 2.f * acc[ii][u * 4 + 3];
                *(float4*)&dist[(long)rloc * NPTS + j0 + tx * 4 + 64 * u] = o;
            }
        }
    }
}

// ---------------- erosion edge-conv (fp32, order-free exact) ----------------
template<int F, int C>
__global__ void erode_kernel(const float* __restrict__ X, int ld, const int* __restrict__ idx,
                             const float* __restrict__ w, float* __restrict__ out, int ldo) {
    __shared__ int nidx[KNN];
    __shared__ float neigh[KNN * C];
    const int tid = threadIdx.x;
    const int row = blockIdx.x;
    if (tid < KNN) nidx[tid] = idx[row * KNN + tid];
    __syncthreads();
    for (int t = tid; t < KNN * C; t += blockDim.x) {
        int k = t / C, c = t % C;
        neigh[t] = X[(long)nidx[k] * ld + c];
    }
    __syncthreads();
    if (tid < F * C) {
        int f = tid / C, c = tid % C;
        float m = neigh[c] - w[f * KNN * C + c];
        for (int k = 1; k < KNN; ++k)
            m = fminf(m, neigh[k * C + c] - w[(f * KNN + k) * C + c]);
        out[(long)row * ldo + tid] = m;
    }
}

// ---------------- fp32 GEMM 128x128 from K-major A (lin1), single-buffer, float4 staging ----------------
// A from AT[k][i] (ld NPTS); B row-major [K][N] with N%128==0; M chunk %128==0; guards on k only.
// Identical loop structure to dist128 (round-12 proven register budget).
template<int RELU>
__global__ __launch_bounds__(256) void gemm128T_kernel(const float* __restrict__ AT,
                                                       const float* __restrict__ B,
                                                       const float* __restrict__ bias, float* __restrict__ Cm,
                                                       int K, int N, int i0base) {
    __shared__ float As[16][132];
    __shared__ float Bs[16][132];
    const int tid = threadIdx.x;
    const int i0 = i0base + blockIdx.y * 128;
    const int j0 = blockIdx.x * 128;
    const int ty = tid >> 4, tx = tid & 15;
    const int lc = tid >> 5;
    const int lr4 = (tid & 31) * 4;

    const float4 z4 = {0.f, 0.f, 0.f, 0.f};
    float4 ra0, ra1, rb0, rb1;
    float acc[8][8];
#pragma unroll
    for (int a = 0; a < 8; ++a)
#pragma unroll
        for (int b = 0; b < 8; ++b) acc[a][b] = 0.f;

    {
        const bool v0 = (lc < K), v1 = (lc + 8 < K);
        ra0 = v0 ? *(const float4*)&AT[(long)lc * NPTS + i0 + lr4] : z4;
        ra1 = v1 ? *(const float4*)&AT[(long)(lc + 8) * NPTS + i0 + lr4] : z4;
        rb0 = v0 ? *(const float4*)&B[(long)lc * N + j0 + lr4] : z4;
        rb1 = v1 ? *(const float4*)&B[(long)(lc + 8) * N + j0 + lr4] : z4;
    }

    for (int k0 = 0; k0 < K; k0 += 16) {
        *(float4*)&As[lc][lr4]     = ra0;
        *(float4*)&As[lc + 8][lr4] = ra1;
        *(float4*)&Bs[lc][lr4]     = rb0;
        *(float4*)&Bs[lc + 8][lr4] = rb1;
        __syncthreads();
        if (k0 + 16 < K) {
            const int c0 = k0 + 16 + lc, c1 = c0 + 8;
            const bool v0 = (c0 < K), v1 = (c1 < K);
            ra0 = v0 ? *(const float4*)&AT[(long)c0 * NPTS + i0 + lr4] : z4;
            ra1 = v1 ? *(const float4*)&AT[(long)c1 * NPTS + i0 + lr4] : z4;
            rb0 = v0 ? *(const float4*)&B[(long)c0 * N + j0 + lr4] : z4;
            rb1 = v1 ? *(const float4*)&B[(long)c1 * N + j0 + lr4] : z4;
        }
#pragma unroll
        for (int kk = 0; kk < 16; ++kk) {
            float4 a0 = *(const float4*)&As[kk][ty * 4];
            float4 a1 = *(const float4*)&As[kk][ty * 4 + 64];
            float4 b0 = *(const float4*)&Bs[kk][tx * 4];
            float4 b1 = *(const float4*)&Bs[kk][tx * 4 + 64];
            float av[8] = {a0.x, a0.y, a0.z, a0.w, a1.x, a1.y, a1.z, a1.w};
            float bv[8] = {b0.x, b0.y, b0.z, b0.w, b1.x, b1.y, b1.z, b1.w};
#pragma unroll
            for (int ii = 0; ii < 8; ++ii)
#pragma unroll
                for (int jj = 0; jj < 8; ++jj)
                    acc[ii][jj] = fmaf(av[ii], bv[jj], acc[ii][jj]);
        }
        __syncthreads();
    }

#pragma unroll
    for (int v = 0; v < 2; ++v) {
#pragma unroll
        for (int rr = 0; rr < 4; ++rr) {
            int iloc = blockIdx.y * 128 + ty * 4 + 64 * v + rr;   // chunk-local row
            int ii = v * 4 + rr;
#pragma unroll
            for (int u = 0; u < 2; ++u) {
                int j = j0 + tx * 4 + 64 * u;
                float4 o;
                o.x = acc[ii][u * 4 + 0] + bias[j + 0];
                o.y = acc[ii][u * 4 + 1] + bias[j + 1];
                o.z = acc[ii][u * 4 + 2] + bias[j + 2];
                o.w = acc[ii][u * 4 + 3] + bias[j + 3];
                if (RELU) {
                    o.x = fmaxf(o.x, 0.f); o.y = fmaxf(o.y, 0.f);
                    o.z = fmaxf(o.z, 0.f); o.w = fmaxf(o.w, 0.f);
                }
                *(float4*)&Cm[(long)iloc * N + j] = o;
            }
        }
    }
    (void)i0;
}

// ---------------- fp32 GEMM 64x64 (layers 2-4), BK=32 prefetch ----------------
template<int RELU>
__global__ __launch_bounds__(256) void gemm_kernel(const float* __restrict__ A, const float* __restrict__ B,
                                                   const float* __restrict__ bias, float* __restrict__ Cm,
                                                   int K, int N) {
    __shared__ float As[32][68];
    __shared__ float Bs[32][68];
    const int tid = threadIdx.x;
    const int i0 = blockIdx.y * 64, j0 = blockIdx.x * 64;
    const int ty = tid >> 4, tx = tid & 15;
    const int la_c = tid & 31, la_r = tid >> 5;
    const int lb_n = tid & 63, lb_k = tid >> 6;

    float ra[8], rb[8];
    float acc[4][4];
#pragma unroll
    for (int a = 0; a < 4; ++a)
#pragma unroll
        for (int b = 0; b < 4; ++b) acc[a][b] = 0.f;

    {
        const bool bn = (j0 + lb_n < N);
#pragma unroll
        for (int q = 0; q < 8; ++q) {
            int r = la_r + 8 * q;
            ra[q] = (la_c < K) ? A[(long)(i0 + r) * K + la_c] : 0.f;
            int kk = lb_k + 4 * q;
            rb[q] = (kk < K && bn) ? B[(long)kk * N + j0 + lb_n] : 0.f;
        }
    }

    for (int k0 = 0; k0 < K; k0 += 32) {
#pragma unroll
        for (int q = 0; q < 8; ++q) {
            As[la_c][la_r + 8 * q] = ra[q];
            Bs[lb_k + 4 * q][lb_n] = rb[q];
        }
        __syncthreads();
        if (k0 + 32 < K) {
            const bool bn = (j0 + lb_n < N);
#pragma unroll
            for (int q = 0; q < 8; ++q) {
                int r = la_r + 8 * q;
                ra[q] = (k0 + 32 + la_c < K) ? A[(long)(i0 + r) * K + k0 + 32 + la_c] : 0.f;
                int kk = k0 + 32 + lb_k + 4 * q;
                rb[q] = (kk < K && bn) ? B[(long)kk * N + j0 + lb_n] : 0.f;
            }
        }
#pragma unroll
        for (int kk = 0; kk < 32; ++kk) {
            float4 a4 = *(const float4*)&As[kk][ty * 4];
            float4 b4 = *(const float4*)&Bs[kk][tx * 4];
            float av[4] = {a4.x, a4.y, a4.z, a4.w};
            float bv[4] = {b4.x, b4.y, b4.z, b4.w};
#pragma unroll
            for (int ii = 0; ii < 4; ++ii)
#pragma unroll
                for (int jj = 0; jj < 4; ++jj)
                    acc[ii][jj] = fmaf(av[ii], bv[jj], acc[ii][jj]);
        }
        __syncthreads();
    }

#pragma unroll
    for (int ii = 0; ii < 4; ++ii) {
        int i = i0 + ty * 4 + ii;
#pragma unroll
        for (int jj = 0; jj < 4; ++jj) {
            int j = j0 + tx * 4 + jj;
            if (j < N) {
                float v = acc[ii][jj] + bias[j];
                if (RELU) v = fmaxf(v, 0.f);
                Cm[(long)i * N + j] = v;
            }
        }
    }
}

// ---------------- log_softmax over 40 cols, wave per row, in place ----------------
__global__ void logsoftmax_kernel(float* __restrict__ out) {
    const int lane = threadIdx.x & 63;
    const int wid = threadIdx.x >> 6;
    const int row = blockIdx.x * 4 + wid;
    float* o = out + (long)row * 40;
    float v = (lane < 40) ? o[lane] : -INFINITY;
    float m = v;
#pragma unroll
    for (int off = 1; off < 64; off <<= 1) m = fmaxf(m, __shfl_xor(m, off));
    float e = (lane < 40) ? expf(v - m) : 0.f;
    float s = e;
#pragma unroll
    for (int off = 1; off < 64; off <<= 1) s += __shfl_xor(s, off);
    float r = (v - m) - logf(s);
    if (lane < 40) o[lane] = r;
}

extern "C" void kernel_launch(void* const* d_in, const int* in_sizes, int n_in,
                              void* d_out, int out_size, void* d_ws, size_t ws_size,
                              hipStream_t stream) {
    (void)in_sizes; (void)n_in; (void)out_size;
    const float* x     = (const float*)d_in[0];
    const float* w1    = (const float*)d_in[1];
    const float* w2    = (const float*)d_in[2];
    const float* w3    = (const float*)d_in[3];
    const float* lin1w = (const float*)d_in[4];
    const float* lin1b = (const float*)d_in[5];
    const float* wa    = (const float*)d_in[6];
    const float* ba    = (const float*)d_in[7];
    const float* wb    = (const float*)d_in[8];
    const float* bb    = (const float*)d_in[9];
    const float* wo    = (const float*)d_in[10];
    const float* bo    = (const float*)d_in[11];
    float* outp = (float*)d_out;

    // ---- ws_size-adaptive layout ----
    char* ws = (char*)d_ws;
    size_t off = 0;
    auto take = [&](size_t bytes) { char* p = ws + off; off += (bytes + 255) & ~(size_t)255; return p; };
    float* x2  = (float*)take((size_t)NPTS * 4);
    int*   idx = (int*)  take((size_t)NPTS * KNN * 4);
    float* h0  = (float*)take((size_t)NPTS * 420 * 4);
    float* sx0 = (float*)take((size_t)NPTS * 4);
    float* sx1 = (float*)take((size_t)NPTS * 4);
    float* sx2 = (float*)take((size_t)NPTS * 4);
    float* XT  = (float*)take((size_t)NPTS * 420 * 4);   // K-major h0 (progressively filled)
    size_t rest = (ws_size > off) ? (ws_size - off) : 0;
    char*  scratch = ws + off;

    int cr = (int)(rest / ((size_t)NPTS * 4));   // fp32 dist chunk rows
    if (cr > 4096) cr = 4096;                    // 128 MB chunk: topk re-read stays L3-resident
    cr &= ~127;
    if (cr < 128) cr = 128;
    float* dist = (float*)scratch;

    int mr = (int)(rest / 5632);                 // fp32 MLP chunk rows
    if (mr > NPTS) mr = NPTS;
    mr &= ~127;
    if (mr < 128) mr = 128;

    dim3 b256(256);
    dim3 b512(NT);
    dim3 grow(NPTS);

    // ---- stage 1: fused knn(x, C=3) -> erode -> x1 = h0[:, 0:60]
    rowsq_np_kernel<3><<<dim3(32), b256, 0, stream>>>(x, 3, x2);
    soa3_kernel<<<dim3(32), b256, 0, stream>>>(x, sx0, sx1, sx2);
    knn3_fused_kernel<<<grow, b512, 0, stream>>>(sx0, sx1, sx2, x2, idx);
    erode_kernel<20, 3><<<grow, dim3(64), 0, stream>>>(x, 3, idx, w1, h0 + 0, 420);

    // ---- stage 2: knn(x1, C=60) -> erode -> x2f = h0[:, 60:180]
    rowsq_np_kernel<60><<<dim3(32), b256, 0, stream>>>(h0, 420, x2);
    transpose_kernel<<<dim3(NPTS / 32, 2), b256, 0, stream>>>(h0, 420, 60, XT);
    for (int r0 = 0; r0 < NPTS; r0 += cr) {
        int rows = (NPTS - r0 < cr) ? (NPTS - r0) : cr;
        dist128_kernel<<<dim3(64, rows / 128), b256, 0, stream>>>(XT, 60, x2, dist, r0);
        topk_kernel<<<dim3(rows), b512, 0, stream>>>(dist, idx, r0);
    }
    erode_kernel<2, 60><<<grow, dim3(128), 0, stream>>>(h0, 420, idx, w2, h0 + 60, 420);

    // ---- stage 3: knn(x2f, C=120) -> erode -> x3 = h0[:, 180:420]
    rowsq_np_kernel<120><<<dim3(32), b256, 0, stream>>>(h0 + 60, 420, x2);
    transpose_kernel<<<dim3(NPTS / 32, 4), b256, 0, stream>>>(h0 + 60, 420, 120, XT + (size_t)60 * NPTS);
    for (int r0 = 0; r0 < NPTS; r0 += cr) {
        int rows = (NPTS - r0 < cr) ? (NPTS - r0) : cr;
        dist128_kernel<<<dim3(64, rows / 128), b256, 0, stream>>>(XT + (size_t)60 * NPTS, 120, x2, dist, r0);
        topk_kernel<<<dim3(rows), b512, 0, stream>>>(dist, idx, r0);
    }
    erode_kernel<2, 120><<<grow, dim3(256), 0, stream>>>(h0 + 60, 420, idx, w3, h0 + 180, 420);

    // ---- finish K-major h0: cols 180..420
    transpose_kernel<<<dim3(NPTS / 32, 8), b256, 0, stream>>>(h0 + 180, 420, 240, XT + (size_t)180 * NPTS);

    // ---- MLP (row-chunked; h1|h2|h3 live in scratch)
    for (int r0 = 0; r0 < NPTS; r0 += mr) {
        int rows = (NPTS - r0 < mr) ? (NPTS - r0) : mr;
        float* h1c = (float*)scratch;
        float* h2c = h1c + (size_t)mr * 1024;
        float* h3c = h2c + (size_t)mr * 256;
        gemm128T_kernel<1><<<dim3(8, rows / 128), b256, 0, stream>>>(XT, lin1w, lin1b, h1c, 420, 1024, r0);
        gemm_kernel<1><<<dim3(4, rows / 64), b256, 0, stream>>>(h1c, wa, ba, h2c, 1024, 256);
        gemm_kernel<1><<<dim3(2, rows / 64), b256, 0, stream>>>(h2c, wb, bb, h3c, 256, 128);
        gemm_kernel<0><<<dim3(1, rows / 64), b256, 0, stream>>>(h3c, wo, bo, outp + (long)r0 * 40, 128, 40);
        logsoftmax_kernel<<<dim3(rows / 4), b256, 0, stream>>>(outp + (long)r0 * 40);
    }
}

// Round 15
// 884.415 us; speedup vs baseline: 1.3851x; 1.1010x over previous
//
#include <hip/hip_runtime.h>
#include <math.h>

#define NPTS 8192
#define KNN 20
#define CAP 256
#define NT 512               // threads for select kernels
#define MK (NPTS / NT)       // 16 keys per thread (registers)
#define NW (NT / 64)         // 8 waves

static __device__ __forceinline__ unsigned long long umin64(unsigned long long a, unsigned long long b) {
    return a < b ? a : b;
}
static __device__ __forceinline__ unsigned umin32(unsigned a, unsigned b) { return a < b ? a : b; }

// ---------------- row squared norms: bit-faithful replica of np.sum(x*x, -1) ----------------
template<int C>
__global__ void rowsq_np_kernel(const float* __restrict__ X, int ld, float* __restrict__ x2) {
#pragma clang fp contract(off)
    int i = blockIdx.x * blockDim.x + threadIdx.x;
    if (i >= NPTS) return;
    const float* row = X + (long)i * ld;
    float res;
    if (C < 8) {
        res = 0.f;
        for (int c = 0; c < C; ++c) res += row[c] * row[c];
    } else {
        float r[8];
#pragma unroll
        for (int j = 0; j < 8; ++j) r[j] = row[j] * row[j];
        int p = 8;
        for (; p < C - (C % 8); p += 8)
#pragma unroll
            for (int j = 0; j < 8; ++j) r[j] += row[p + j] * row[p + j];
        res = ((r[0] + r[1]) + (r[2] + r[3])) + ((r[4] + r[5]) + (r[6] + r[7]));
        for (; p < C; ++p) res += row[p] * row[p];
    }
    x2[i] = res;
}

// ---------------- X -> SoA (C=3) ----------------
__global__ void soa3_kernel(const float* __restrict__ X, float* __restrict__ X0,
                            float* __restrict__ X1, float* __restrict__ X2) {
    int i = blockIdx.x * blockDim.x + threadIdx.x;
    if (i < NPTS) { X0[i] = X[3 * i]; X1[i] = X[3 * i + 1]; X2[i] = X[3 * i + 2]; }
}

// ---------------- slab transpose: X (row-major, ld) cols[0..C) -> XT[c][j] ----------------
__global__ __launch_bounds__(256) void transpose_kernel(const float* __restrict__ X, int ld, int C,
                                                        float* __restrict__ XT) {
    __shared__ float t[32][33];
    const int jb = blockIdx.x * 32;
    const int cb = blockIdx.y * 32;
    const int tx = threadIdx.x & 31, ty = threadIdx.x >> 5;
#pragma unroll
    for (int k = 0; k < 4; ++k) {
        int j = jb + ty + 8 * k;
        int c = cb + tx;
        t[ty + 8 * k][tx] = (c < C) ? X[(long)j * ld + c] : 0.f;
    }
    __syncthreads();
#pragma unroll
    for (int k = 0; k < 4; ++k) {
        int c = cb + ty + 8 * k;
        int j = jb + tx;
        if (c < C) XT[(long)c * NPTS + j] = t[tx][ty + 8 * k];
    }
}

// ---------------- register-resident count of keys <= B ----------------
__device__ __forceinline__ int count_le_reg(const unsigned* k, unsigned B, int* scal) {
    const int tid = threadIdx.x;
    int cnt = 0;
#pragma unroll
    for (int m = 0; m < MK; ++m) cnt += (k[m] <= B) ? 1 : 0;
#pragma unroll
    for (int o = 32; o >= 1; o >>= 1) cnt += __shfl_down(cnt, (unsigned)o);
    if ((tid & 63) == 0) scal[tid >> 6] = cnt;
    __syncthreads();
    int tot = 0;
#pragma unroll
    for (int w = 0; w < NW; ++w) tot += scal[w];
    __syncthreads();
    return tot;
}

// ---------------- exact top-K via min-scan sample threshold, keys in REGISTERS ----------------
// Extraction: single parallel rank pass over candidates (all u64 distinct -> ranks are a
// bijection; the KNN smallest land at ranks 0..KNN-1 in ascending (key,idx) order —
// provably identical output to the serial 20-round extraction).
__device__ __forceinline__ void select20_reg(unsigned* k, unsigned* ured,
                                             unsigned long long* cand, int* scal,
                                             long row, int* __restrict__ idx_out) {
    const int tid = threadIdx.x;
    unsigned s = k[0];              // one sample per thread (j = tid)
    unsigned B; int c;
    for (;;) {
        unsigned m = s;
#pragma unroll
        for (int o = 32; o >= 1; o >>= 1) m = umin32(m, __shfl_down(m, (unsigned)o));
        if ((tid & 63) == 0) ured[tid >> 6] = m;
        __syncthreads();
        B = ured[0];
#pragma unroll
        for (int w = 1; w < NW; ++w) B = umin32(B, ured[w]);
        __syncthreads();
        c = count_le_reg(k, B, scal);
        if (c >= KNN) break;
        if (s <= B) s = 0xFFFFFFFFu;   // deactivate exhausted samples
    }
    if (tid == 0) scal[8] = 0;
    __syncthreads();

    if (c <= CAP) {
#pragma unroll
        for (int m = 0; m < MK; ++m) {
            if (k[m] <= B) {
                int j = tid + NT * m;
                int p = atomicAdd(&scal[8], 1);    // p < c <= CAP guaranteed
                cand[p] = (((unsigned long long)k[m]) << 32) | (unsigned)j;
            }
        }
        __syncthreads();
        const int nc = scal[8];
        if (tid < nc) {
            const unsigned long long mine = cand[tid];
            int r = 0;
            for (int q = 0; q < nc; ++q)           // broadcast LDS reads, conflict-free
                r += (cand[q] < mine) ? 1 : 0;
            if (r < KNN)
                idx_out[row * KNN + r] = (int)(unsigned)(mine & 0xFFFFFFFFull);
        }
    } else {
        // exact fallback (massive ties) — not expected; cand[0..NW) reused as partials
        for (int it = 0; it < KNN; ++it) {
            unsigned long long best = ~0ull;
#pragma unroll
            for (int m = 0; m < MK; ++m)
                best = umin64(best, (((unsigned long long)k[m]) << 32) | (unsigned)(tid + NT * m));
#pragma unroll
            for (int o = 1; o < 64; o <<= 1) best = umin64(best, __shfl_xor(best, o));
            if ((tid & 63) == 0) cand[tid >> 6] = best;
            __syncthreads();
            unsigned long long g = cand[0];
#pragma unroll
            for (int w = 1; w < NW; ++w) g = umin64(g, cand[w]);
            int j = (int)(unsigned)(g & 0xFFFFFFFFull);
            if (tid == 0) idx_out[row * KNN + it] = j;
            __syncthreads();
            int mi = j / NT;
#pragma unroll
            for (int m = 0; m < MK; ++m)
                if (m == mi && tid == (j & (NT - 1))) k[m] = 0xFFFFFFFFu;
            __syncthreads();
        }
    }
}

// ---------------- stage-1 fused: C=3 distances (SoA) + top-K, keys in registers ----------------
__global__ __launch_bounds__(NT) void knn3_fused_kernel(const float* __restrict__ X0,
                                                        const float* __restrict__ X1,
                                                        const float* __restrict__ X2,
                                                        const float* __restrict__ x2,
                                                        int* __restrict__ idx_out) {
    __shared__ unsigned ured[NW];
    __shared__ unsigned long long cand[CAP];
    __shared__ int scal[16];
    unsigned k[MK];
    const int tid = threadIdx.x;
    const int row = blockIdx.x;
    const float xi0 = X0[row], xi1 = X1[row], xi2 = X2[row];
    const float x2i = x2[row];

#pragma unroll
    for (int m = 0; m < MK; ++m) {
        int j = tid + NT * m;
        float accv = 0.f;                       // identical ascending-c fmaf chain
        accv = fmaf(xi0, X0[j], accv);
        accv = fmaf(xi1, X1[j], accv);
        accv = fmaf(xi2, X2[j], accv);
        float d = (x2i + x2[j]) - 2.f * accv;
        unsigned u = __float_as_uint(d);
        k[m] = (u & 0x80000000u) ? ~u : (u | 0x80000000u);
    }
    select20_reg(k, ured, cand, scal, row, idx_out);
}

// ---------------- top-K from materialized dist rows, keys in registers ----------------
__global__ __launch_bounds__(NT) void topk_kernel(const float* __restrict__ dist, int* __restrict__ idx_out,
                                                  int rowbase) {
    __shared__ unsigned ured[NW];
    __shared__ unsigned long long cand[CAP];
    __shared__ int scal[16];
    unsigned k[MK];
    const int tid = threadIdx.x;
    const long row = rowbase + blockIdx.x;
    const float* drow = dist + (long)blockIdx.x * NPTS;

#pragma unroll
    for (int m = 0; m < MK; ++m) {
        unsigned u = __float_as_uint(drow[tid + NT * m]);
        k[m] = (u & 0x80000000u) ? ~u : (u | 0x80000000u);
    }
    select20_reg(k, ured, cand, scal, row, idx_out);
}

// ---------------- pairwise distance (fp32), 128x128 tile, 8x8 microtile, BK=16 prefetch ----------------
// SINGLE-buffer LDS (proven: 96 VGPR). Staging from K-major XT[c][j]: float4 coalesced
// global loads + b128 LDS writes. 16B-stride LDS reads (2-way = free).
// Bit-exact: per-element ascending-k fmaf chains; pads fmaf(0,0,acc).
__global__ __launch_bounds__(256) void dist128_kernel(const float* __restrict__ XT, int C,
                                                      const float* __restrict__ x2,
                                                      float* __restrict__ dist, int i0base) {
    __shared__ float As[16][132];
    __shared__ float Bs[16][132];
    const int tid = threadIdx.x;
    const int i0 = i0base + blockIdx.y * 128;
    const int j0 = blockIdx.x * 128;
    const int ty = tid >> 4, tx = tid & 15;
    const int lc = tid >> 5;            // loader col 0..7 (and +8)
    const int lr4 = (tid & 31) * 4;     // loader row group

    const float4 z4 = {0.f, 0.f, 0.f, 0.f};
    float4 ra0, ra1, rb0, rb1;
    float acc[8][8];
#pragma unroll
    for (int a = 0; a < 8; ++a)
#pragma unroll
        for (int b = 0; b < 8; ++b) acc[a][b] = 0.f;

    {
        const bool v0 = (lc < C), v1 = (lc + 8 < C);
        ra0 = v0 ? *(const float4*)&XT[(long)lc * NPTS + i0 + lr4] : z4;
        ra1 = v1 ? *(const float4*)&XT[(long)(lc + 8) * NPTS + i0 + lr4] : z4;
        rb0 = v0 ? *(const float4*)&XT[(long)lc * NPTS + j0 + lr4] : z4;
        rb1 = v1 ? *(const float4*)&XT[(long)(lc + 8) * NPTS + j0 + lr4] : z4;
    }

    for (int k0 = 0; k0 < C; k0 += 16) {
        *(float4*)&As[lc][lr4]     = ra0;
        *(float4*)&As[lc + 8][lr4] = ra1;
        *(float4*)&Bs[lc][lr4]     = rb0;
        *(float4*)&Bs[lc + 8][lr4] = rb1;
        __syncthreads();
        if (k0 + 16 < C) {
            const int c0 = k0 + 16 + lc, c1 = c0 + 8;
            const bool v0 = (c0 < C), v1 = (c1 < C);
            ra0 = v0 ? *(const float4*)&XT[(long)c0 * NPTS + i0 + lr4] : z4;
            ra1 = v1 ? *(const float4*)&XT[(long)c1 * NPTS + i0 + lr4] : z4;
            rb0 = v0 ? *(const float4*)&XT[(long)c0 * NPTS + j0 + lr4] : z4;
            rb1 = v1 ? *(const float4*)&XT[(long)c1 * NPTS + j0 + lr4] : z4;
        }
#pragma unroll
        for (int kk = 0; kk < 16; ++kk) {
            float4 a0 = *(const float4*)&As[kk][ty * 4];
            float4 a1 = *(const float4*)&As[kk][ty * 4 + 64];
            float4 b0 = *(const float4*)&Bs[kk][tx * 4];
            float4 b1 = *(const float4*)&Bs[kk][tx * 4 + 64];
            float av[8] = {a0.x, a0.y, a0.z, a0.w, a1.x, a1.y, a1.z, a1.w};
            float bv[8] = {b0.x, b0.y, b0.z, b0.w, b1.x, b1.y, b1.z, b1.w};
#pragma unroll
            for (int ii = 0; ii < 8; ++ii)
#pragma unroll
                for (int jj = 0; jj < 8; ++jj)
                    acc[ii][jj] = fmaf(av[ii], bv[jj], acc[ii][jj]);
        }
        __syncthreads();
    }

    float xj[8];
#pragma unroll
    for (int u = 0; u < 2; ++u)
#pragma unroll
        for (int cc = 0; cc < 4; ++cc) xj[u * 4 + cc] = x2[j0 + tx * 4 + 64 * u + cc];
#pragma unroll
    for (int v = 0; v < 2; ++v) {
#pragma unroll
        for (int rr = 0; rr < 4; ++rr) {
            int rloc = blockIdx.y * 128 + ty * 4 + 64 * v + rr;
            float xi = x2[i0base + rloc];
            int ii = v * 4 + rr;
#pragma unroll
            for (int u = 0; u < 2; ++u) {
                float4 o;
                o.x = (xi + xj[u * 4 + 0]) - 2.f * acc[ii][u * 4 + 0];
                o.y = (xi + xj[u * 4 + 1]) - 2.f * acc[ii][u * 4 + 1];
                o.z = (xi + xj[u * 4 + 2]) - 2.f * acc[ii][u * 4 + 2];
                o.w = (xi + xj[u * 4 + 3]) - 2.f * acc[ii][u * 4 + 3];
                *(float4*)&dist[(long)rloc * NPTS + j0 + tx * 4 + 64 * u] = o;
            }
        }
    }
}

// ---------------- erosion edge-conv (fp32, order-free exact) ----------------
template<int F, int C>
__global__ void erode_kernel(const float* __restrict__ X, int ld, const int* __restrict__ idx,
                             const float* __restrict__ w, float* __restrict__ out, int ldo) {
    __shared__ int nidx[KNN];
    __shared__ float neigh[KNN * C];
    const int tid = threadIdx.x;
    const int row = blockIdx.x;
    if (tid < KNN) nidx[tid] = idx[row * KNN + tid];
    __syncthreads();
    for (int t = tid; t < KNN * C; t += blockDim.x) {
        int k = t / C, c = t % C;
        neigh[t] = X[(long)nidx[k] * ld + c];
    }
    __syncthreads();
    if (tid < F * C) {
        int f = tid / C, c = tid % C;
        float m = neigh[c] - w[f * KNN * C + c];
        for (int k = 1; k < KNN; ++k)
            m = fminf(m, neigh[k * C + c] - w[(f * KNN + k) * C + c]);
        out[(long)row * ldo + tid] = m;
    }
}

// ---------------- fp32 GEMM 128x128 from K-major A (lin1), single-buffer, float4 staging ----------------
template<int RELU>
__global__ __launch_bounds__(256) void gemm128T_kernel(const float* __restrict__ AT,
                                                       const float* __restrict__ B,
                                                       const float* __restrict__ bias, float* __restrict__ Cm,
                                                       int K, int N, int i0base) {
    __shared__ float As[16][132];
    __shared__ float Bs[16][132];
    const int tid = threadIdx.x;
    const int i0 = i0base + blockIdx.y * 128;
    const int j0 = blockIdx.x * 128;
    const int ty = tid >> 4, tx = tid & 15;
    const int lc = tid >> 5;
    const int lr4 = (tid & 31) * 4;

    const float4 z4 = {0.f, 0.f, 0.f, 0.f};
    float4 ra0, ra1, rb0, rb1;
    float acc[8][8];
#pragma unroll
    for (int a = 0; a < 8; ++a)
#pragma unroll
        for (int b = 0; b < 8; ++b) acc[a][b] = 0.f;

    {
        const bool v0 = (lc < K), v1 = (lc + 8 < K);
        ra0 = v0 ? *(const float4*)&AT[(long)lc * NPTS + i0 + lr4] : z4;
        ra1 = v1 ? *(const float4*)&AT[(long)(lc + 8) * NPTS + i0 + lr4] : z4;
        rb0 = v0 ? *(const float4*)&B[(long)lc * N + j0 + lr4] : z4;
        rb1 = v1 ? *(const float4*)&B[(long)(lc + 8) * N + j0 + lr4] : z4;
    }

    for (int k0 = 0; k0 < K; k0 += 16) {
        *(float4*)&As[lc][lr4]     = ra0;
        *(float4*)&As[lc + 8][lr4] = ra1;
        *(float4*)&Bs[lc][lr4]     = rb0;
        *(float4*)&Bs[lc + 8][lr4] = rb1;
        __syncthreads();
        if (k0 + 16 < K) {
            const int c0 = k0 + 16 + lc, c1 = c0 + 8;
            const bool v0 = (c0 < K), v1 = (c1 < K);
            ra0 = v0 ? *(const float4*)&AT[(long)c0 * NPTS + i0 + lr4] : z4;
            ra1 = v1 ? *(const float4*)&AT[(long)c1 * NPTS + i0 + lr4] : z4;
            rb0 = v0 ? *(const float4*)&B[(long)c0 * N + j0 + lr4] : z4;
            rb1 = v1 ? *(const float4*)&B[(long)c1 * N + j0 + lr4] : z4;
        }
#pragma unroll
        for (int kk = 0; kk < 16; ++kk) {
            float4 a0 = *(const float4*)&As[kk][ty * 4];
            float4 a1 = *(const float4*)&As[kk][ty * 4 + 64];
            float4 b0 = *(const float4*)&Bs[kk][tx * 4];
            float4 b1 = *(const float4*)&Bs[kk][tx * 4 + 64];
            float av[8] = {a0.x, a0.y, a0.z, a0.w, a1.x, a1.y, a1.z, a1.w};
            float bv[8] = {b0.x, b0.y, b0.z, b0.w, b1.x, b1.y, b1.z, b1.w};
#pragma unroll
            for (int ii = 0; ii < 8; ++ii)
#pragma unroll
                for (int jj = 0; jj < 8; ++jj)
                    acc[ii][jj] = fmaf(av[ii], bv[jj], acc[ii][jj]);
        }
        __syncthreads();
    }

#pragma unroll
    for (int v = 0; v < 2; ++v) {
#pragma unroll
        for (int rr = 0; rr < 4; ++rr) {
            int iloc = blockIdx.y * 128 + ty * 4 + 64 * v + rr;   // chunk-local row
            int ii = v * 4 + rr;
#pragma unroll
            for (int u = 0; u < 2; ++u) {
                int j = j0 + tx * 4 + 64 * u;
                float4 o;
                o.x = acc[ii][u * 4 + 0] + bias[j + 0];
                o.y = acc[ii][u * 4 + 1] + bias[j + 1];
                o.z = acc[ii][u * 4 + 2] + bias[j + 2];
                o.w = acc[ii][u * 4 + 3] + bias[j + 3];
                if (RELU) {
                    o.x = fmaxf(o.x, 0.f); o.y = fmaxf(o.y, 0.f);
                    o.z = fmaxf(o.z, 0.f); o.w = fmaxf(o.w, 0.f);
                }
                *(float4*)&Cm[(long)iloc * N + j] = o;
            }
        }
    }
    (void)i0;
}

// ---------------- fp32 GEMM 64x64 (layers 2-4), BK=32 prefetch ----------------
template<int RELU>
__global__ __launch_bounds__(256) void gemm_kernel(const float* __restrict__ A, const float* __restrict__ B,
                                                   const float* __restrict__ bias, float* __restrict__ Cm,
                                                   int K, int N) {
    __shared__ float As[32][68];
    __shared__ float Bs[32][68];
    const int tid = threadIdx.x;
    const int i0 = blockIdx.y * 64, j0 = blockIdx.x * 64;
    const int ty = tid >> 4, tx = tid & 15;
    const int la_c = tid & 31, la_r = tid >> 5;
    const int lb_n = tid & 63, lb_k = tid >> 6;

    float ra[8], rb[8];
    float acc[4][4];
#pragma unroll
    for (int a = 0; a < 4; ++a)
#pragma unroll
        for (int b = 0; b < 4; ++b) acc[a][b] = 0.f;

    {
        const bool bn = (j0 + lb_n < N);
#pragma unroll
        for (int q = 0; q < 8; ++q) {
            int r = la_r + 8 * q;
            ra[q] = (la_c < K) ? A[(long)(i0 + r) * K + la_c] : 0.f;
            int kk = lb_k + 4 * q;
            rb[q] = (kk < K && bn) ? B[(long)kk * N + j0 + lb_n] : 0.f;
        }
    }

    for (int k0 = 0; k0 < K; k0 += 32) {
#pragma unroll
        for (int q = 0; q < 8; ++q) {
            As[la_c][la_r + 8 * q] = ra[q];
            Bs[lb_k + 4 * q][lb_n] = rb[q];
        }
        __syncthreads();
        if (k0 + 32 < K) {
            const bool bn = (j0 + lb_n < N);
#pragma unroll
            for (int q = 0; q < 8; ++q) {
                int r = la_r + 8 * q;
                ra[q] = (k0 + 32 + la_c < K) ? A[(long)(i0 + r) * K + k0 + 32 + la_c] : 0.f;
                int kk = k0 + 32 + lb_k + 4 * q;
                rb[q] = (kk < K && bn) ? B[(long)kk * N + j0 + lb_n] : 0.f;
            }
        }
#pragma unroll
        for (int kk = 0; kk < 32; ++kk) {
            float4 a4 = *(const float4*)&As[kk][ty * 4];
            float4 b4 = *(const float4*)&Bs[kk][tx * 4];
            float av[4] = {a4.x, a4.y, a4.z, a4.w};
            float bv[4] = {b4.x, b4.y, b4.z, b4.w};
#pragma unroll
            for (int ii = 0; ii < 4; ++ii)
#pragma unroll
                for (int jj = 0; jj < 4; ++jj)
                    acc[ii][jj] = fmaf(av[ii], bv[jj], acc[ii][jj]);
        }
        __syncthreads();
    }

#pragma unroll
    for (int ii = 0; ii < 4; ++ii) {
        int i = i0 + ty * 4 + ii;
#pragma unroll
        for (int jj = 0; jj < 4; ++jj) {
            int j = j0 + tx * 4 + jj;
            if (j < N) {
                float v = acc[ii][jj] + bias[j];
                if (RELU) v = fmaxf(v, 0.f);
                Cm[(long)i * N + j] = v;
            }
        }
    }
}

// ---------------- log_softmax over 40 cols, wave per row, in place ----------------
__global__ void logsoftmax_kernel(float* __restrict__ out) {
    const int lane = threadIdx.x & 63;
    const int wid = threadIdx.x >> 6;
    const int row = blockIdx.x * 4 + wid;
    float* o = out + (long)row * 40;
    float v = (lane < 40) ? o[lane] : -INFINITY;
    float m = v;
#pragma unroll
    for (int off = 1; off < 64; off <<= 1) m = fmaxf(m, __shfl_xor(m, off));
    float e = (lane < 40) ? expf(v - m) : 0.f;
    float s = e;
#pragma unroll
    for (int off = 1; off < 64; off <<= 1) s += __shfl_xor(s, off);
    float r = (v - m) - logf(s);
    if (lane < 40) o[lane] = r;
}

extern "C" void kernel_launch(void* const* d_in, const int* in_sizes, int n_in,
                              void* d_out, int out_size, void* d_ws, size_t ws_size,
                              hipStream_t stream) {
    (void)in_sizes; (void)n_in; (void)out_size;
    const float* x     = (const float*)d_in[0];
    const float* w1    = (const float*)d_in[1];
    const float* w2    = (const float*)d_in[2];
    const float* w3    = (const float*)d_in[3];
    const float* lin1w = (const float*)d_in[4];
    const float* lin1b = (const float*)d_in[5];
    const float* wa    = (const float*)d_in[6];
    const float* ba    = (const float*)d_in[7];
    const float* wb    = (const float*)d_in[8];
    const float* bb    = (const float*)d_in[9];
    const float* wo    = (const float*)d_in[10];
    const float* bo    = (const float*)d_in[11];
    float* outp = (float*)d_out;

    // ---- ws_size-adaptive layout ----
    char* ws = (char*)d_ws;
    size_t off = 0;
    auto take = [&](size_t bytes) { char* p = ws + off; off += (bytes + 255) & ~(size_t)255; return p; };
    float* x2  = (float*)take((size_t)NPTS * 4);
    int*   idx = (int*)  take((size_t)NPTS * KNN * 4);
    float* h0  = (float*)take((size_t)NPTS * 420 * 4);
    float* sx0 = (float*)take((size_t)NPTS * 4);
    float* sx1 = (float*)take((size_t)NPTS * 4);
    float* sx2 = (float*)take((size_t)NPTS * 4);
    float* XT  = (float*)take((size_t)NPTS * 420 * 4);   // K-major h0 (progressively filled)
    size_t rest = (ws_size > off) ? (ws_size - off) : 0;
    char*  scratch = ws + off;

    int cr = (int)(rest / ((size_t)NPTS * 4));   // fp32 dist chunk rows
    if (cr > 4096) cr = 4096;                    // 128 MB chunk: topk re-read stays L3-resident
    cr &= ~127;
    if (cr < 128) cr = 128;
    float* dist = (float*)scratch;

    int mr = (int)(rest / 5632);                 // fp32 MLP chunk rows
    if (mr > NPTS) mr = NPTS;
    mr &= ~127;
    if (mr < 128) mr = 128;

    dim3 b256(256);
    dim3 b512(NT);
    dim3 grow(NPTS);

    // ---- stage 1: fused knn(x, C=3) -> erode -> x1 = h0[:, 0:60]
    rowsq_np_kernel<3><<<dim3(32), b256, 0, stream>>>(x, 3, x2);
    soa3_kernel<<<dim3(32), b256, 0, stream>>>(x, sx0, sx1, sx2);
    knn3_fused_kernel<<<grow, b512, 0, stream>>>(sx0, sx1, sx2, x2, idx);
    erode_kernel<20, 3><<<grow, dim3(64), 0, stream>>>(x, 3, idx, w1, h0 + 0, 420);

    // ---- stage 2: knn(x1, C=60) -> erode -> x2f = h0[:, 60:180]
    rowsq_np_kernel<60><<<dim3(32), b256, 0, stream>>>(h0, 420, x2);
    transpose_kernel<<<dim3(NPTS / 32, 2), b256, 0, stream>>>(h0, 420, 60, XT);
    for (int r0 = 0; r0 < NPTS; r0 += cr) {
        int rows = (NPTS - r0 < cr) ? (NPTS - r0) : cr;
        dist128_kernel<<<dim3(64, rows / 128), b256, 0, stream>>>(XT, 60, x2, dist, r0);
        topk_kernel<<<dim3(rows), b512, 0, stream>>>(dist, idx, r0);
    }
    erode_kernel<2, 60><<<grow, dim3(128), 0, stream>>>(h0, 420, idx, w2, h0 + 60, 420);

    // ---- stage 3: knn(x2f, C=120) -> erode -> x3 = h0[:, 180:420]
    rowsq_np_kernel<120><<<dim3(32), b256, 0, stream>>>(h0 + 60, 420, x2);
    transpose_kernel<<<dim3(NPTS / 32, 4), b256, 0, stream>>>(h0 + 60, 420, 120, XT + (size_t)60 * NPTS);
    for (int r0 = 0; r0 < NPTS; r0 += cr) {
        int rows = (NPTS - r0 < cr) ? (NPTS - r0) : cr;
        dist128_kernel<<<dim3(64, rows / 128), b256, 0, stream>>>(XT + (size_t)60 * NPTS, 120, x2, dist, r0);
        topk_kernel<<<dim3(rows), b512, 0, stream>>>(dist, idx, r0);
    }
    erode_kernel<2, 120><<<grow, dim3(256), 0, stream>>>(h0 + 60, 420, idx, w3, h0 + 180, 420);

    // ---- finish K-major h0: cols 180..420
    transpose_kernel<<<dim3(NPTS / 32, 8), b256, 0, stream>>>(h0 + 180, 420, 240, XT + (size_t)180 * NPTS);

    // ---- MLP (row-chunked; h1|h2|h3 live in scratch)
    for (int r0 = 0; r0 < NPTS; r0 += mr) {
        int rows = (NPTS - r0 < mr) ? (NPTS - r0) : mr;
        float* h1c = (float*)scratch;
        float* h2c = h1c + (size_t)mr * 1024;
        float* h3c = h2c + (size_t)mr * 256;
        gemm128T_kernel<1><<<dim3(8, rows / 128), b256, 0, stream>>>(XT, lin1w, lin1b, h1c, 420, 1024, r0);
        gemm_kernel<1><<<dim3(4, rows / 64), b256, 0, stream>>>(h1c, wa, ba, h2c, 1024, 256);
        gemm_kernel<1><<<dim3(2, rows / 64), b256, 0, stream>>>(h2c, wb, bb, h3c, 256, 128);
        gemm_kernel<0><<<dim3(1, rows / 64), b256, 0, stream>>>(h3c, wo, bo, outp + (long)r0 * 40, 128, 40);
        logsoftmax_kernel<<<dim3(rows / 4), b256, 0, stream>>>(outp + (long)r0 * 40);
    }
}